// Round 1
// baseline (361.531 us; speedup 1.0000x reference)
//
#include <hip/hip_runtime.h>

#define B_   4
#define L_   2048
#define D_   256
#define H_   8
#define DH_  32
#define MLP_ 1024

typedef __attribute__((ext_vector_type(8))) short  short8;
typedef __attribute__((ext_vector_type(4))) float  f32x4;

union FragU { short8 v; struct { unsigned long long lo, hi; } q; };

__device__ __forceinline__ unsigned short f2bf(float f) {
  unsigned u = __float_as_uint(f);
  u += 0x7fffu + ((u >> 16) & 1u);
  return (unsigned short)(u >> 16);
}

__device__ __forceinline__ unsigned long long pack4(float a, float b, float c, float d) {
  return (unsigned long long)f2bf(a) | ((unsigned long long)f2bf(b) << 16)
       | ((unsigned long long)f2bf(c) << 32) | ((unsigned long long)f2bf(d) << 48);
}

// ---------------- elementwise converts ----------------

__global__ void cvt_k(const float* __restrict__ in, unsigned short* __restrict__ out, int n4) {
  const int i = blockIdx.x * blockDim.x + threadIdx.x;
  if (i < n4) {
    const float4 v = *(const float4*)(in + (size_t)i * 4);
    *(unsigned long long*)(out + (size_t)i * 4) = pack4(v.x, v.y, v.z, v.w);
  }
}

// out[c][r] = bf16(in[r][c])  (weights stored transposed so GEMM B-frags are contiguous)
__global__ void tpose_k(const float* __restrict__ in, unsigned short* __restrict__ out, int R, int C) {
  const int i = blockIdx.x * blockDim.x + threadIdx.x;
  if (i < R * C) {
    const int r = i / C, c = i - r * C;
    out[(size_t)c * R + r] = f2bf(in[i]);
  }
}

// ---------------- GEMM: C[M,N] = A[M,K] * Bt[N,K]^T  (+ epilogue) ----------------
// MODE 0: qkv  (bias bqkv, scatter to q/k/v [B,H,L,DH], q *= DH^-0.5)
// MODE 1: proj (bias bo, + resid x -> fp32 y)
// MODE 2: mlp1 (bias b1, relu -> bf16 h, ld 1024)
// MODE 3: mlp2 (bias b2, + resid x1 -> fp32 y)
template <int MODE>
__launch_bounds__(256)
__global__ void gemm_k(const unsigned short* __restrict__ A,
                       const unsigned short* __restrict__ Bt,
                       const float* __restrict__ bias,
                       const float* __restrict__ resid,
                       float* __restrict__ outf,
                       unsigned short* __restrict__ outb0,
                       unsigned short* __restrict__ outb1,
                       unsigned short* __restrict__ outb2,
                       int K)
{
  __shared__ unsigned short As[128][32];
  __shared__ unsigned short Bs[128][32];
  const int tid  = threadIdx.x;
  const int lane = tid & 63, wv = tid >> 6;
  const int wr = wv >> 1, wc = wv & 1;
  const int lr = lane & 15, g = lane >> 4;
  const int m0 = blockIdx.y * 128, n0 = blockIdx.x * 128;
  const int srow = tid >> 2, skc = (tid & 3) * 8;

  f32x4 acc[4][4];
#pragma unroll
  for (int i = 0; i < 4; ++i)
#pragma unroll
    for (int j = 0; j < 4; ++j) acc[i][j] = (f32x4)(0.f);

  for (int k0 = 0; k0 < K; k0 += 32) {
    *(int4*)&As[srow][skc]      = *(const int4*)(A  + (size_t)(m0 + srow)      * K + k0 + skc);
    *(int4*)&As[srow + 64][skc] = *(const int4*)(A  + (size_t)(m0 + srow + 64) * K + k0 + skc);
    *(int4*)&Bs[srow][skc]      = *(const int4*)(Bt + (size_t)(n0 + srow)      * K + k0 + skc);
    *(int4*)&Bs[srow + 64][skc] = *(const int4*)(Bt + (size_t)(n0 + srow + 64) * K + k0 + skc);
    __syncthreads();
    FragU af[4], bf[4];
#pragma unroll
    for (int mi = 0; mi < 4; ++mi) {
      const unsigned short* r = &As[wr * 64 + mi * 16 + lr][0];
      af[mi].q.lo = *(const unsigned long long*)(r + 4 * g);
      af[mi].q.hi = *(const unsigned long long*)(r + 16 + 4 * g);
    }
#pragma unroll
    for (int ni = 0; ni < 4; ++ni) {
      const unsigned short* r = &Bs[wc * 64 + ni * 16 + lr][0];
      bf[ni].q.lo = *(const unsigned long long*)(r + 4 * g);
      bf[ni].q.hi = *(const unsigned long long*)(r + 16 + 4 * g);
    }
#pragma unroll
    for (int mi = 0; mi < 4; ++mi)
#pragma unroll
      for (int ni = 0; ni < 4; ++ni)
        acc[mi][ni] = __builtin_amdgcn_mfma_f32_16x16x32_bf16(af[mi].v, bf[ni].v, acc[mi][ni], 0, 0, 0);
    __syncthreads();
  }

#pragma unroll
  for (int mi = 0; mi < 4; ++mi) {
#pragma unroll
    for (int ni = 0; ni < 4; ++ni) {
      const int n = n0 + wc * 64 + ni * 16 + lr;
      const float bv = bias[n];
#pragma unroll
      for (int r = 0; r < 4; ++r) {
        const int m = m0 + wr * 64 + mi * 16 + 4 * g + r;
        float val = acc[mi][ni][r] + bv;
        if constexpr (MODE == 0) {
          const int s = n >> 8, hh = (n >> 5) & 7, dh = n & 31;
          const size_t o = ((size_t)((m >> 11) * H_ + hh) * L_ + (m & (L_ - 1))) * DH_ + dh;
          if (s == 0)      outb0[o] = f2bf(val * 0.17677669529663687f);
          else if (s == 1) outb1[o] = f2bf(val);
          else             outb2[o] = f2bf(val);
        } else if constexpr (MODE == 1) {
          const size_t o = (size_t)m * D_ + n;
          outf[o] = val + resid[o];
        } else if constexpr (MODE == 2) {
          outb0[(size_t)m * MLP_ + n] = f2bf(fmaxf(val, 0.f));
        } else {
          const size_t o = (size_t)m * D_ + n;
          outf[o] = val + resid[o];
        }
      }
    }
  }
}

// ---------------- flash attention (bf16 MFMA, online softmax) ----------------
__launch_bounds__(256)
__global__ void attn_k(const unsigned short* __restrict__ qb,
                       const unsigned short* __restrict__ kb,
                       const unsigned short* __restrict__ vb,
                       const int* __restrict__ mask,
                       const float* __restrict__ relb,
                       unsigned short* __restrict__ aout)
{
  __shared__ unsigned short Ks[64][32];
  __shared__ unsigned short Vt[32][64];
  __shared__ float biasv[33];
  __shared__ float maskv[64];
  const int tid = threadIdx.x;
  const int lane = tid & 63, wv = tid >> 6;
  const int lr = lane & 15, g = lane >> 4;
  const int bh = blockIdx.y, b = bh >> 3, h = bh & 7;
  const size_t bhoff = (size_t)bh * (L_ * DH_);
  if (tid < 33) biasv[tid] = relb[tid * H_ + h];
  const int qbase = blockIdx.x * 64 + wv * 16;
  const int qglob = qbase + lr;
  FragU qf;
  {
    const unsigned short* qr = qb + bhoff + (size_t)qglob * DH_;
    qf.q.lo = *(const unsigned long long*)(qr + 4 * g);
    qf.q.hi = *(const unsigned long long*)(qr + 16 + 4 * g);
  }
  f32x4 O0 = (f32x4)(0.f), O1 = (f32x4)(0.f);
  float m_run = -1e30f, ssum = 0.f;
  const int srow = tid >> 2, skc = (tid & 3) * 8;
  const f32x4 z4 = (f32x4)(0.f);

  for (int ch = 0; ch < L_ / 64; ++ch) {
    const int kvbase = ch * 64;
    {
      const size_t go = bhoff + (size_t)(kvbase + srow) * DH_ + skc;
      *(int4*)&Ks[srow][skc] = *(const int4*)(kb + go);
      int4 vvv = *(const int4*)(vb + go);
      const unsigned short* vs = (const unsigned short*)&vvv;
#pragma unroll
      for (int j = 0; j < 8; ++j) Vt[skc + j][srow] = vs[j];
      if (tid < 64) maskv[tid] = mask[b * L_ + kvbase + tid] ? 1.f : 0.f;
    }
    __syncthreads();

    // S^T[j][q] = sum_d K[j][d] * Q[q][d]   (4 tiles of 16 j each, K-dim = DH = 32)
    f32x4 sT[4];
#pragma unroll
    for (int jt = 0; jt < 4; ++jt) {
      FragU kf;
      const unsigned short* kr = &Ks[jt * 16 + lr][0];
      kf.q.lo = *(const unsigned long long*)(kr + 4 * g);
      kf.q.hi = *(const unsigned long long*)(kr + 16 + 4 * g);
      sT[jt] = __builtin_amdgcn_mfma_f32_16x16x32_bf16(kf.v, qf.v, z4, 0, 0, 0);
    }

    // bias + mask + online softmax (this lane owns q = qbase+lr, j = kvbase + jt*16 + 4g + r)
    float p[4][4];
    float mloc = -1e30f;
#pragma unroll
    for (int jt = 0; jt < 4; ++jt) {
#pragma unroll
      for (int r = 0; r < 4; ++r) {
        const int jl = jt * 16 + 4 * g + r;
        int rel = (kvbase + jl) - qglob;
        rel = rel < -16 ? -16 : (rel > 16 ? 16 : rel);
        float s = sT[jt][r] + biasv[rel + 16];
        s = (maskv[jl] != 0.f) ? -1e9f : s;
        p[jt][r] = s;
        mloc = fmaxf(mloc, s);
      }
    }
    mloc = fmaxf(mloc, __shfl_xor(mloc, 16));
    mloc = fmaxf(mloc, __shfl_xor(mloc, 32));
    const float m_new = fmaxf(m_run, mloc);
    const float corr = __expf(m_run - m_new);
    float psum = 0.f;
#pragma unroll
    for (int jt = 0; jt < 4; ++jt)
#pragma unroll
      for (int r = 0; r < 4; ++r) { const float e = __expf(p[jt][r] - m_new); p[jt][r] = e; psum += e; }
    psum += __shfl_xor(psum, 16);
    psum += __shfl_xor(psum, 32);
    ssum = ssum * corr + psum;
    m_run = m_new;
    // rescale O (O rows live at q = 4g+r -> fetch per-row corr via shfl)
#pragma unroll
    for (int r = 0; r < 4; ++r) {
      const float c = __shfl(corr, 4 * g + r);
      O0[r] *= c; O1[r] *= c;
    }
    // P fragments: D-layout of S^T is exactly the PV A-frag slot set
    short8 a0, a1;
#pragma unroll
    for (int i = 0; i < 4; ++i) {
      a0[i]     = (short)f2bf(p[0][i]);
      a0[4 + i] = (short)f2bf(p[1][i]);
      a1[i]     = (short)f2bf(p[2][i]);
      a1[4 + i] = (short)f2bf(p[3][i]);
    }
#pragma unroll
    for (int dt = 0; dt < 2; ++dt) {
      const unsigned short* vr = &Vt[dt * 16 + lr][0];
      FragU v0, v1;
      v0.q.lo = *(const unsigned long long*)(vr + 4 * g);
      v0.q.hi = *(const unsigned long long*)(vr + 16 + 4 * g);
      v1.q.lo = *(const unsigned long long*)(vr + 32 + 4 * g);
      v1.q.hi = *(const unsigned long long*)(vr + 48 + 4 * g);
      f32x4 accv = dt ? O1 : O0;
      accv = __builtin_amdgcn_mfma_f32_16x16x32_bf16(a0, v0.v, accv, 0, 0, 0);
      accv = __builtin_amdgcn_mfma_f32_16x16x32_bf16(a1, v1.v, accv, 0, 0, 0);
      if (dt) O1 = accv; else O0 = accv;
    }
    __syncthreads();
  }

#pragma unroll
  for (int r = 0; r < 4; ++r) {
    const float sden = __shfl(ssum, 4 * g + r);
    const float inv = 1.f / sden;
    const int qo = qbase + 4 * g + r;
    unsigned short* orow = aout + ((size_t)(b * L_ + qo)) * D_ + h * DH_;
    orow[lr]      = f2bf(O0[r] * inv);
    orow[16 + lr] = f2bf(O1[r] * inv);
  }
}

// ---------------- LayerNorm (one wave per row) ----------------
__launch_bounds__(256)
__global__ void ln_k(const float* __restrict__ y, const float* __restrict__ gg,
                     const float* __restrict__ bb, float* __restrict__ outf,
                     unsigned short* __restrict__ outb)
{
  const int tid = threadIdx.x, lane = tid & 63, wv = tid >> 6;
  const int row = blockIdx.x * 4 + wv;
  const size_t base = (size_t)row * D_ + lane * 4;
  const float4 v = *(const float4*)(y + base);
  float s = v.x + v.y + v.z + v.w;
#pragma unroll
  for (int m = 1; m < 64; m <<= 1) s += __shfl_xor(s, m);
  const float mu = s * (1.f / D_);
  const float dx = v.x - mu, dy = v.y - mu, dz = v.z - mu, dw = v.w - mu;
  float q = dx * dx + dy * dy + dz * dz + dw * dw;
#pragma unroll
  for (int m = 1; m < 64; m <<= 1) q += __shfl_xor(q, m);
  const float rstd = rsqrtf(q * (1.f / D_) + 1e-5f);
  const float4 g4 = *(const float4*)(gg + lane * 4);
  const float4 b4 = *(const float4*)(bb + lane * 4);
  float4 o;
  o.x = dx * rstd * g4.x + b4.x;
  o.y = dy * rstd * g4.y + b4.y;
  o.z = dz * rstd * g4.z + b4.z;
  o.w = dw * rstd * g4.w + b4.w;
  *(float4*)(outf + base) = o;
  if (outb) *(unsigned long long*)(outb + base) = pack4(o.x, o.y, o.z, o.w);
}

// ---------------- launch ----------------
extern "C" void kernel_launch(void* const* d_in, const int* in_sizes, int n_in,
                              void* d_out, int out_size, void* d_ws, size_t ws_size,
                              hipStream_t stream) {
  (void)in_sizes; (void)n_in; (void)out_size; (void)ws_size;
  const float* x    = (const float*)d_in[0];
  const int*   mask = (const int*)d_in[1];
  const float* Wqkv = (const float*)d_in[2];
  const float* bqkv = (const float*)d_in[3];
  const float* Wo   = (const float*)d_in[4];
  const float* bo   = (const float*)d_in[5];
  const float* ln1g = (const float*)d_in[6];
  const float* ln1b = (const float*)d_in[7];
  const float* W1   = (const float*)d_in[8];
  const float* b1   = (const float*)d_in[9];
  const float* W2   = (const float*)d_in[10];
  const float* b2   = (const float*)d_in[11];
  const float* ln2g = (const float*)d_in[12];
  const float* ln2b = (const float*)d_in[13];
  const float* relb = (const float*)d_in[14];

  size_t off = 0;
  char* wsb = (char*)d_ws;
  auto carve = [&](size_t bytes) -> void* {
    void* p = wsb + off;
    off += (bytes + 255) & ~(size_t)255;
    return p;
  };
  const size_t tokb = (size_t)B_ * L_;              // 8192 tokens
  unsigned short* xb    = (unsigned short*)carve(tokb * D_ * 2);
  unsigned short* qb    = (unsigned short*)carve(tokb * D_ * 2);
  unsigned short* kbuf  = (unsigned short*)carve(tokb * D_ * 2);
  unsigned short* vbuf  = (unsigned short*)carve(tokb * D_ * 2);
  unsigned short* attnb = (unsigned short*)carve(tokb * D_ * 2);
  unsigned short* wqkvt = (unsigned short*)carve((size_t)3 * D_ * D_ * 2);
  unsigned short* wot   = (unsigned short*)carve((size_t)D_ * D_ * 2);
  unsigned short* w1t   = (unsigned short*)carve((size_t)D_ * MLP_ * 2);
  unsigned short* w2t   = (unsigned short*)carve((size_t)D_ * MLP_ * 2);
  float*          ybuf  = (float*)carve(tokb * D_ * 4);
  float*          x1    = (float*)carve(tokb * D_ * 4);
  unsigned short* x1b   = (unsigned short*)carve(tokb * D_ * 2);
  unsigned short* hbuf  = (unsigned short*)carve(tokb * MLP_ * 2);

  // converts
  cvt_k<<<(tokb * D_ / 4 + 255) / 256, 256, 0, stream>>>(x, xb, (int)(tokb * D_ / 4));
  tpose_k<<<(D_ * 3 * D_ + 255) / 256, 256, 0, stream>>>(Wqkv, wqkvt, D_, 3 * D_);
  tpose_k<<<(D_ * D_ + 255) / 256, 256, 0, stream>>>(Wo, wot, D_, D_);
  tpose_k<<<(D_ * MLP_ + 255) / 256, 256, 0, stream>>>(W1, w1t, D_, MLP_);
  tpose_k<<<(MLP_ * D_ + 255) / 256, 256, 0, stream>>>(W2, w2t, MLP_, D_);

  // qkv projection
  gemm_k<0><<<dim3(3 * D_ / 128, tokb / 128), 256, 0, stream>>>(
      xb, wqkvt, bqkv, nullptr, nullptr, qb, kbuf, vbuf, D_);
  // attention
  attn_k<<<dim3(L_ / 64, B_ * H_), 256, 0, stream>>>(qb, kbuf, vbuf, mask, relb, attnb);
  // output projection + residual
  gemm_k<1><<<dim3(D_ / 128, tokb / 128), 256, 0, stream>>>(
      attnb, wot, bo, x, ybuf, nullptr, nullptr, nullptr, D_);
  ln_k<<<tokb / 4, 256, 0, stream>>>(ybuf, ln1g, ln1b, x1, x1b);
  // MLP
  gemm_k<2><<<dim3(MLP_ / 128, tokb / 128), 256, 0, stream>>>(
      x1b, w1t, b1, nullptr, nullptr, hbuf, nullptr, nullptr, D_);
  gemm_k<3><<<dim3(D_ / 128, tokb / 128), 256, 0, stream>>>(
      hbuf, w2t, b2, x1, ybuf, nullptr, nullptr, nullptr, MLP_);
  ln_k<<<tokb / 4, 256, 0, stream>>>(ybuf, ln2g, ln2b, (float*)d_out, nullptr);
}

// Round 2
// 175.918 us; speedup vs baseline: 2.0551x; 2.0551x over previous
//
#include <hip/hip_runtime.h>

#define B_   4
#define L_   2048
#define D_   256
#define H_   8
#define DH_  32
#define MLP_ 1024

typedef __attribute__((ext_vector_type(8))) short  short8;
typedef __attribute__((ext_vector_type(4))) float  f32x4;

union FragU { short8 v; struct { unsigned long long lo, hi; } q; };

__device__ __forceinline__ unsigned short f2bf(float f) {
  unsigned u = __float_as_uint(f);
  u += 0x7fffu + ((u >> 16) & 1u);
  return (unsigned short)(u >> 16);
}

__device__ __forceinline__ unsigned long long pack4(float a, float b, float c, float d) {
  return (unsigned long long)f2bf(a) | ((unsigned long long)f2bf(b) << 16)
       | ((unsigned long long)f2bf(c) << 32) | ((unsigned long long)f2bf(d) << 48);
}

// ---------------- elementwise converts ----------------

__global__ void cvt_k(const float* __restrict__ in, unsigned short* __restrict__ out, int n4) {
  const int i = blockIdx.x * blockDim.x + threadIdx.x;
  if (i < n4) {
    const float4 v = *(const float4*)(in + (size_t)i * 4);
    *(unsigned long long*)(out + (size_t)i * 4) = pack4(v.x, v.y, v.z, v.w);
  }
}

// out[c][r] = bf16(in[r][c])
__global__ void tpose_k(const float* __restrict__ in, unsigned short* __restrict__ out, int R, int C) {
  const int i = blockIdx.x * blockDim.x + threadIdx.x;
  if (i < R * C) {
    const int r = i / C, c = i - r * C;
    out[(size_t)c * R + r] = f2bf(in[i]);
  }
}

// ---------------- GEMM: C[M,N] = A[M,K] * Bt[N,K]^T  (+ epilogue) ----------------
// MODE 0: qkv  (bias, scatter q/k -> [B,H,L,DH] (q scaled), v -> [B,H,DH,L])
// MODE 1: proj (bias bo, + resid x -> fp32 y)
// MODE 2: mlp1 (bias b1, relu -> bf16 h)
// MODE 3: mlp2 (bias b2, + resid x1 -> fp32 y)
template <int MODE>
__launch_bounds__(256)
__global__ void gemm_k(const unsigned short* __restrict__ A,
                       const unsigned short* __restrict__ Bt,
                       const float* __restrict__ bias,
                       const float* __restrict__ resid,
                       float* __restrict__ outf,
                       unsigned short* __restrict__ outb0,
                       unsigned short* __restrict__ outb1,
                       unsigned short* __restrict__ outb2,
                       int K)
{
  __shared__ alignas(16) unsigned short As[128 * 64];
  __shared__ alignas(16) unsigned short Bs[128 * 64];
  const int tid  = threadIdx.x;
  const int lane = tid & 63, wv = tid >> 6;
  const int wr = wv >> 1, wc = wv & 1;
  const int lr = lane & 15, g = lane >> 4;
  const int m0 = blockIdx.y * 128, n0 = blockIdx.x * 128;
  const int srow = tid >> 3, sc8 = tid & 7;

  f32x4 acc[4][4];
#pragma unroll
  for (int i = 0; i < 4; ++i)
#pragma unroll
    for (int j = 0; j < 4; ++j) acc[i][j] = (f32x4)(0.f);

  for (int k0 = 0; k0 < K; k0 += 64) {
#pragma unroll
    for (int i = 0; i < 4; ++i) {
      const int row = srow + 32 * i;
      const int dst = row * 64 + ((sc8 ^ (row & 7)) * 8);
      *(int4*)&As[dst] = *(const int4*)(A  + (size_t)(m0 + row) * K + k0 + sc8 * 8);
      *(int4*)&Bs[dst] = *(const int4*)(Bt + (size_t)(n0 + row) * K + k0 + sc8 * 8);
    }
    __syncthreads();
#pragma unroll
    for (int kk = 0; kk < 2; ++kk) {
      FragU af[4], bf[4];
#pragma unroll
      for (int mi = 0; mi < 4; ++mi) {
        const int row = wr * 64 + mi * 16 + lr;
        const int sw = (row & 7) << 3;
        af[mi].q.lo = *(const unsigned long long*)&As[row * 64 + ((kk * 32 + 4 * g) ^ sw)];
        af[mi].q.hi = *(const unsigned long long*)&As[row * 64 + ((kk * 32 + 16 + 4 * g) ^ sw)];
      }
#pragma unroll
      for (int ni = 0; ni < 4; ++ni) {
        const int row = wc * 64 + ni * 16 + lr;
        const int sw = (row & 7) << 3;
        bf[ni].q.lo = *(const unsigned long long*)&Bs[row * 64 + ((kk * 32 + 4 * g) ^ sw)];
        bf[ni].q.hi = *(const unsigned long long*)&Bs[row * 64 + ((kk * 32 + 16 + 4 * g) ^ sw)];
      }
#pragma unroll
      for (int mi = 0; mi < 4; ++mi)
#pragma unroll
        for (int ni = 0; ni < 4; ++ni)
          acc[mi][ni] = __builtin_amdgcn_mfma_f32_16x16x32_bf16(af[mi].v, bf[ni].v, acc[mi][ni], 0, 0, 0);
    }
    __syncthreads();
  }

#pragma unroll
  for (int mi = 0; mi < 4; ++mi) {
#pragma unroll
    for (int ni = 0; ni < 4; ++ni) {
      const int n = n0 + wc * 64 + ni * 16 + lr;
      const float bv = bias[n];
#pragma unroll
      for (int r = 0; r < 4; ++r) {
        const int m = m0 + wr * 64 + mi * 16 + 4 * g + r;
        float val = acc[mi][ni][r] + bv;
        if constexpr (MODE == 0) {
          const int s = n >> 8, hh = (n >> 5) & 7, dh = n & 31;
          const int bb = m >> 11, l = m & (L_ - 1);
          if (s == 0) {
            outb0[((size_t)(bb * H_ + hh) * L_ + l) * DH_ + dh] = f2bf(val * 0.17677669529663687f);
          } else if (s == 1) {
            outb1[((size_t)(bb * H_ + hh) * L_ + l) * DH_ + dh] = f2bf(val);
          } else {
            outb2[((size_t)(bb * H_ + hh) * DH_ + dh) * L_ + l] = f2bf(val);
          }
        } else if constexpr (MODE == 1) {
          const size_t o = (size_t)m * D_ + n;
          outf[o] = val + resid[o];
        } else if constexpr (MODE == 2) {
          outb0[(size_t)m * MLP_ + n] = f2bf(fmaxf(val, 0.f));
        } else {
          const size_t o = (size_t)m * D_ + n;
          outf[o] = val + resid[o];
        }
      }
    }
  }
}

// ---------------- flash attention ----------------
// 4 waves * 32 q rows = 128 q / block; KV chunk 64.
__launch_bounds__(256)
__global__ void attn_k(const unsigned short* __restrict__ qb,
                       const unsigned short* __restrict__ kb,
                       const unsigned short* __restrict__ vT,
                       const int* __restrict__ mask,
                       const float* __restrict__ relb,
                       unsigned short* __restrict__ aout)
{
  __shared__ alignas(16) unsigned short Ks[64 * 40];   // padded rows: 80B -> conflict-free
  __shared__ alignas(16) unsigned short Vs[32 * 64];   // XOR-swizzled rows
  __shared__ alignas(16) float biasv[36];
  __shared__ alignas(16) float maskadd[64];
  const int tid = threadIdx.x;
  const int lane = tid & 63, wv = tid >> 6;
  const int lr = lane & 15, g = lane >> 4;
  const int bh = blockIdx.y, b = bh >> 3, h = bh & 7;
  const size_t bhoff = (size_t)bh * (L_ * DH_);
  if (tid < 33) biasv[tid] = relb[tid * H_ + h];
  const float bias_lo = relb[h];
  const float bias_hi = relb[32 * H_ + h];
  const int qw0 = blockIdx.x * 128 + wv * 32;

  FragU qf[2];
#pragma unroll
  for (int t = 0; t < 2; ++t) {
    const unsigned short* qr = qb + bhoff + (size_t)(qw0 + t * 16 + lr) * DH_;
    qf[t].q.lo = *(const unsigned long long*)(qr + 4 * g);
    qf[t].q.hi = *(const unsigned long long*)(qr + 16 + 4 * g);
  }
  f32x4 O[2][2];
#pragma unroll
  for (int t = 0; t < 2; ++t) { O[t][0] = (f32x4)(0.f); O[t][1] = (f32x4)(0.f); }
  float m_run[2] = {-1e30f, -1e30f};
  float ssum[2] = {0.f, 0.f};
  const f32x4 z4 = (f32x4)(0.f);
  const int krow = tid >> 2, kc8 = tid & 3;
  const int vrow = tid >> 3, vc8 = tid & 7;

  for (int ch = 0; ch < L_ / 64; ++ch) {
    const int kvbase = ch * 64;
    *(int4*)&Ks[krow * 40 + kc8 * 8] =
        *(const int4*)(kb + bhoff + (size_t)(kvbase + krow) * DH_ + kc8 * 8);
    *(int4*)&Vs[vrow * 64 + ((vc8 ^ (vrow & 7)) * 8)] =
        *(const int4*)(vT + ((size_t)bh * DH_ + vrow) * L_ + kvbase + vc8 * 8);
    if (tid < 64) maskadd[tid] = mask[b * L_ + kvbase + tid] ? -1e9f : 0.f;
    __syncthreads();

    // chunk-shared fragments
    FragU kf[4];
#pragma unroll
    for (int jt = 0; jt < 4; ++jt) {
      const int base = (jt * 16 + lr) * 40;
      kf[jt].q.lo = *(const unsigned long long*)&Ks[base + 4 * g];
      kf[jt].q.hi = *(const unsigned long long*)&Ks[base + 16 + 4 * g];
    }
    FragU vf[2][2];
#pragma unroll
    for (int dt = 0; dt < 2; ++dt)
#pragma unroll
      for (int jh = 0; jh < 2; ++jh) {
        const int row = dt * 16 + lr;
        const int sw = (row & 7) << 3;
        vf[dt][jh].q.lo = *(const unsigned long long*)&Vs[row * 64 + ((jh * 32 + 4 * g) ^ sw)];
        vf[dt][jh].q.hi = *(const unsigned long long*)&Vs[row * 64 + ((jh * 32 + 16 + 4 * g) ^ sw)];
      }
    f32x4 mf[4];
#pragma unroll
    for (int jt = 0; jt < 4; ++jt) mf[jt] = *(const f32x4*)(maskadd + jt * 16 + 4 * g);

#pragma unroll
    for (int t = 0; t < 2; ++t) {
      const int q0 = qw0 + t * 16;
      f32x4 sT[4];
#pragma unroll
      for (int jt = 0; jt < 4; ++jt)
        sT[jt] = __builtin_amdgcn_mfma_f32_16x16x32_bf16(kf[jt].v, qf[t].v, z4, 0, 0, 0);

      float p[4][4];
      const int dlt = kvbase - q0;
      if (dlt >= 32 || dlt <= -80) {          // whole tile beyond the +-16 ramp
        const float badd = (dlt > 0) ? bias_hi : bias_lo;
#pragma unroll
        for (int jt = 0; jt < 4; ++jt)
#pragma unroll
          for (int r = 0; r < 4; ++r) p[jt][r] = sT[jt][r] + badd + mf[jt][r];
      } else {
#pragma unroll
        for (int jt = 0; jt < 4; ++jt)
#pragma unroll
          for (int r = 0; r < 4; ++r) {
            int rel = kvbase + jt * 16 + 4 * g + r - (q0 + lr);
            rel = rel < -16 ? -16 : (rel > 16 ? 16 : rel);
            p[jt][r] = sT[jt][r] + biasv[rel + 16] + mf[jt][r];
          }
      }
      float mloc = -3e38f;
#pragma unroll
      for (int jt = 0; jt < 4; ++jt)
#pragma unroll
        for (int r = 0; r < 4; ++r) mloc = fmaxf(mloc, p[jt][r]);
      mloc = fmaxf(mloc, __shfl_xor(mloc, 16));
      mloc = fmaxf(mloc, __shfl_xor(mloc, 32));
      float m_new = m_run[t];
      if (!__all(mloc <= m_run[t] + 8.f)) {   // defer-max: skip rescale on small growth
        m_new = fmaxf(m_run[t], mloc);
        const float corr = __expf(m_run[t] - m_new);
#pragma unroll
        for (int r = 0; r < 4; ++r) {
          const float c = __shfl(corr, 4 * g + r);
          O[t][0][r] *= c; O[t][1][r] *= c;
        }
        ssum[t] *= corr;
        m_run[t] = m_new;
      }
      float psum = 0.f;
#pragma unroll
      for (int jt = 0; jt < 4; ++jt)
#pragma unroll
        for (int r = 0; r < 4; ++r) {
          const float e = __expf(p[jt][r] - m_new);
          p[jt][r] = e; psum += e;
        }
      psum += __shfl_xor(psum, 16);
      psum += __shfl_xor(psum, 32);
      ssum[t] += psum;

      short8 a0, a1;
#pragma unroll
      for (int i = 0; i < 4; ++i) {
        a0[i]     = (short)f2bf(p[0][i]);
        a0[4 + i] = (short)f2bf(p[1][i]);
        a1[i]     = (short)f2bf(p[2][i]);
        a1[4 + i] = (short)f2bf(p[3][i]);
      }
      O[t][0] = __builtin_amdgcn_mfma_f32_16x16x32_bf16(a0, vf[0][0].v, O[t][0], 0, 0, 0);
      O[t][0] = __builtin_amdgcn_mfma_f32_16x16x32_bf16(a1, vf[0][1].v, O[t][0], 0, 0, 0);
      O[t][1] = __builtin_amdgcn_mfma_f32_16x16x32_bf16(a0, vf[1][0].v, O[t][1], 0, 0, 0);
      O[t][1] = __builtin_amdgcn_mfma_f32_16x16x32_bf16(a1, vf[1][1].v, O[t][1], 0, 0, 0);
    }
    __syncthreads();
  }

#pragma unroll
  for (int t = 0; t < 2; ++t)
#pragma unroll
    for (int r = 0; r < 4; ++r) {
      const float sden = __shfl(ssum[t], 4 * g + r);
      const float inv = 1.f / sden;
      const int qo = qw0 + t * 16 + 4 * g + r;
      unsigned short* orow = aout + ((size_t)(b * L_ + qo)) * D_ + h * DH_;
      orow[lr]      = f2bf(O[t][0][r] * inv);
      orow[16 + lr] = f2bf(O[t][1][r] * inv);
    }
}

// ---------------- LayerNorm (one wave per row) ----------------
__launch_bounds__(256)
__global__ void ln_k(const float* __restrict__ y, const float* __restrict__ gg,
                     const float* __restrict__ bb, float* __restrict__ outf,
                     unsigned short* __restrict__ outb)
{
  const int tid = threadIdx.x, lane = tid & 63, wv = tid >> 6;
  const int row = blockIdx.x * 4 + wv;
  const size_t base = (size_t)row * D_ + lane * 4;
  const float4 v = *(const float4*)(y + base);
  float s = v.x + v.y + v.z + v.w;
#pragma unroll
  for (int m = 1; m < 64; m <<= 1) s += __shfl_xor(s, m);
  const float mu = s * (1.f / D_);
  const float dx = v.x - mu, dy = v.y - mu, dz = v.z - mu, dw = v.w - mu;
  float q = dx * dx + dy * dy + dz * dz + dw * dw;
#pragma unroll
  for (int m = 1; m < 64; m <<= 1) q += __shfl_xor(q, m);
  const float rstd = rsqrtf(q * (1.f / D_) + 1e-5f);
  const float4 g4 = *(const float4*)(gg + lane * 4);
  const float4 b4 = *(const float4*)(bb + lane * 4);
  float4 o;
  o.x = dx * rstd * g4.x + b4.x;
  o.y = dy * rstd * g4.y + b4.y;
  o.z = dz * rstd * g4.z + b4.z;
  o.w = dw * rstd * g4.w + b4.w;
  *(float4*)(outf + base) = o;
  if (outb) *(unsigned long long*)(outb + base) = pack4(o.x, o.y, o.z, o.w);
}

// ---------------- launch ----------------
extern "C" void kernel_launch(void* const* d_in, const int* in_sizes, int n_in,
                              void* d_out, int out_size, void* d_ws, size_t ws_size,
                              hipStream_t stream) {
  (void)in_sizes; (void)n_in; (void)out_size; (void)ws_size;
  const float* x    = (const float*)d_in[0];
  const int*   mask = (const int*)d_in[1];
  const float* Wqkv = (const float*)d_in[2];
  const float* bqkv = (const float*)d_in[3];
  const float* Wo   = (const float*)d_in[4];
  const float* bo   = (const float*)d_in[5];
  const float* ln1g = (const float*)d_in[6];
  const float* ln1b = (const float*)d_in[7];
  const float* W1   = (const float*)d_in[8];
  const float* b1   = (const float*)d_in[9];
  const float* W2   = (const float*)d_in[10];
  const float* b2   = (const float*)d_in[11];
  const float* ln2g = (const float*)d_in[12];
  const float* ln2b = (const float*)d_in[13];
  const float* relb = (const float*)d_in[14];

  size_t off = 0;
  char* wsb = (char*)d_ws;
  auto carve = [&](size_t bytes) -> void* {
    void* p = wsb + off;
    off += (bytes + 255) & ~(size_t)255;
    return p;
  };
  const size_t tokb = (size_t)B_ * L_;
  unsigned short* xb    = (unsigned short*)carve(tokb * D_ * 2);
  unsigned short* qb    = (unsigned short*)carve(tokb * D_ * 2);
  unsigned short* kbuf  = (unsigned short*)carve(tokb * D_ * 2);
  unsigned short* vTb   = (unsigned short*)carve(tokb * D_ * 2);
  unsigned short* attnb = (unsigned short*)carve(tokb * D_ * 2);
  unsigned short* wqkvt = (unsigned short*)carve((size_t)3 * D_ * D_ * 2);
  unsigned short* wot   = (unsigned short*)carve((size_t)D_ * D_ * 2);
  unsigned short* w1t   = (unsigned short*)carve((size_t)D_ * MLP_ * 2);
  unsigned short* w2t   = (unsigned short*)carve((size_t)D_ * MLP_ * 2);
  float*          ybuf  = (float*)carve(tokb * D_ * 4);
  float*          x1    = (float*)carve(tokb * D_ * 4);
  unsigned short* x1b   = (unsigned short*)carve(tokb * D_ * 2);
  unsigned short* hbuf  = (unsigned short*)carve(tokb * MLP_ * 2);

  cvt_k<<<(tokb * D_ / 4 + 255) / 256, 256, 0, stream>>>(x, xb, (int)(tokb * D_ / 4));
  tpose_k<<<(D_ * 3 * D_ + 255) / 256, 256, 0, stream>>>(Wqkv, wqkvt, D_, 3 * D_);
  tpose_k<<<(D_ * D_ + 255) / 256, 256, 0, stream>>>(Wo, wot, D_, D_);
  tpose_k<<<(D_ * MLP_ + 255) / 256, 256, 0, stream>>>(W1, w1t, D_, MLP_);
  tpose_k<<<(MLP_ * D_ + 255) / 256, 256, 0, stream>>>(W2, w2t, MLP_, D_);

  gemm_k<0><<<dim3(3 * D_ / 128, tokb / 128), 256, 0, stream>>>(
      xb, wqkvt, bqkv, nullptr, nullptr, qb, kbuf, vTb, D_);
  attn_k<<<dim3(L_ / 128, B_ * H_), 256, 0, stream>>>(qb, kbuf, vTb, mask, relb, attnb);
  gemm_k<1><<<dim3(D_ / 128, tokb / 128), 256, 0, stream>>>(
      attnb, wot, bo, x, ybuf, nullptr, nullptr, nullptr, D_);
  ln_k<<<tokb / 4, 256, 0, stream>>>(ybuf, ln1g, ln1b, x1, x1b);
  gemm_k<2><<<dim3(MLP_ / 128, tokb / 128), 256, 0, stream>>>(
      x1b, w1t, b1, nullptr, nullptr, hbuf, nullptr, nullptr, D_);
  gemm_k<3><<<dim3(D_ / 128, tokb / 128), 256, 0, stream>>>(
      hbuf, w2t, b2, x1, ybuf, nullptr, nullptr, nullptr, MLP_);
  ln_k<<<tokb / 4, 256, 0, stream>>>(ybuf, ln2g, ln2b, (float*)d_out, nullptr);
}

// Round 3
// 147.683 us; speedup vs baseline: 2.4480x; 1.1912x over previous
//
#include <hip/hip_runtime.h>

#define B_   4
#define L_   2048
#define D_   256
#define H_   8
#define DH_  32
#define MLP_ 1024
#define LOG2E 1.4426950408889634f

typedef __attribute__((ext_vector_type(8))) short  short8;
typedef __attribute__((ext_vector_type(4))) float  f32x4;

union FragU { short8 v; struct { unsigned long long lo, hi; } q; unsigned u[4]; };

__device__ __forceinline__ unsigned short f2bf(float f) {
  unsigned u = __float_as_uint(f);
  u += 0x7fffu + ((u >> 16) & 1u);
  return (unsigned short)(u >> 16);
}

__device__ __forceinline__ unsigned long long pack4(float a, float b, float c, float d) {
  return (unsigned long long)f2bf(a) | ((unsigned long long)f2bf(b) << 16)
       | ((unsigned long long)f2bf(c) << 32) | ((unsigned long long)f2bf(d) << 48);
}

__device__ __forceinline__ unsigned cvt_pk_bf16(float lo, float hi) {
  unsigned r;
  asm("v_cvt_pk_bf16_f32 %0, %1, %2" : "=v"(r) : "v"(lo), "v"(hi));
  return r;
}

__device__ __forceinline__ float fexp2(float x) {
#if __has_builtin(__builtin_amdgcn_exp2f)
  return __builtin_amdgcn_exp2f(x);
#else
  return exp2f(x);
#endif
}

// global -> LDS direct, 16B per lane (dest must be wave-uniform base; lane scatter is +lane*16B)
#define GLL16(gp, lp) __builtin_amdgcn_global_load_lds( \
    (const __attribute__((address_space(1))) void*)(gp), \
    (__attribute__((address_space(3))) void*)(lp), 16, 0, 0)

// ---------------- converts ----------------

__global__ void cvt_k(const float* __restrict__ in, unsigned short* __restrict__ out, int n4) {
  const int i = blockIdx.x * blockDim.x + threadIdx.x;
  if (i < n4) {
    const float4 v = *(const float4*)(in + (size_t)i * 4);
    *(unsigned long long*)(out + (size_t)i * 4) = pack4(v.x, v.y, v.z, v.w);
  }
}

// all four weight transposes in one launch: out[c][r] = bf16(in[r][c])
__global__ void prep_w(const float* __restrict__ Wqkv, const float* __restrict__ Wo,
                       const float* __restrict__ W1, const float* __restrict__ W2,
                       unsigned short* __restrict__ wqkvt, unsigned short* __restrict__ wot,
                       unsigned short* __restrict__ w1t, unsigned short* __restrict__ w2t) {
  const int i = blockIdx.x * 256 + threadIdx.x;
  if (i < 196608) {            // Wqkv 256x768
    const int r = i / 768, c = i - r * 768;
    wqkvt[(size_t)c * 256 + r] = f2bf(Wqkv[i]);
  } else if (i < 262144) {     // Wo 256x256
    const int j = i - 196608, r = j >> 8, c = j & 255;
    wot[(size_t)c * 256 + r] = f2bf(Wo[j]);
  } else if (i < 524288) {     // W1 256x1024
    const int j = i - 262144, r = j >> 10, c = j & 1023;
    w1t[(size_t)c * 256 + r] = f2bf(W1[j]);
  } else {                     // W2 1024x256
    const int j = i - 524288, r = j >> 8, c = j & 255;
    w2t[(size_t)c * 1024 + r] = f2bf(W2[j]);
  }
}

// ---------------- GEMM: C[M,N] = A[M,K] * Bt[N,K]^T (+ epilogue) ----------------
// MODE 0: qkv  (bias, scatter q/k -> [B,H,L,DH] (q scaled by DH^-.5*log2e), v -> [B,H,DH,L])
// MODE 1: proj (bias bo, + resid x -> fp32 y)
// MODE 2: mlp1 (bias b1, relu -> bf16 h)
// MODE 3: mlp2 (bias b2, + resid x1 -> fp32 y)
template <int MODE, int TM, int TN>
__launch_bounds__(256)
__global__ void gemm_k(const unsigned short* __restrict__ A,
                       const unsigned short* __restrict__ Bt,
                       const float* __restrict__ bias,
                       const float* __restrict__ resid,
                       float* __restrict__ outf,
                       unsigned short* __restrict__ outb0,
                       unsigned short* __restrict__ outb1,
                       unsigned short* __restrict__ outb2,
                       int K)
{
  constexpr int MI = TM / 32, NI = TN / 32;
  __shared__ alignas(16) unsigned short As[TM * 64];
  __shared__ alignas(16) unsigned short Bs[TN * 64];
  const int tid  = threadIdx.x;
  const int lane = tid & 63, wv = tid >> 6;
  const int wr = wv >> 1, wc = wv & 1;
  const int lr = lane & 15, g = lane >> 4;
  const int m0 = blockIdx.y * TM, n0 = blockIdx.x * TN;
  const int l8 = lane >> 3, jj = lane & 7;

  f32x4 acc[MI][NI];
#pragma unroll
  for (int i = 0; i < MI; ++i)
#pragma unroll
    for (int j = 0; j < NI; ++j) acc[i][j] = (f32x4)(0.f);

  for (int k0 = 0; k0 < K; k0 += 64) {
    // pre-swizzled-source global_load_lds staging (linear LDS dest, XOR'd source col)
#pragma unroll
    for (int i = 0; i < MI; ++i) {
      const int row = i * 32 + wv * 8 + l8;
      GLL16(A + (size_t)(m0 + row) * K + k0 + ((jj ^ (row & 7)) * 8),
            &As[(i * 256 + wv * 64) * 8]);
    }
#pragma unroll
    for (int i = 0; i < NI; ++i) {
      const int row = i * 32 + wv * 8 + l8;
      GLL16(Bt + (size_t)(n0 + row) * K + k0 + ((jj ^ (row & 7)) * 8),
            &Bs[(i * 256 + wv * 64) * 8]);
    }
    __syncthreads();
#pragma unroll
    for (int kk = 0; kk < 2; ++kk) {
      FragU af[MI], bf[NI];
#pragma unroll
      for (int mi = 0; mi < MI; ++mi) {
        const int row = wr * (TM / 2) + mi * 16 + lr;
        const int sw = (row & 7) << 3;
        af[mi].q.lo = *(const unsigned long long*)&As[row * 64 + ((kk * 32 + 4 * g) ^ sw)];
        af[mi].q.hi = *(const unsigned long long*)&As[row * 64 + ((kk * 32 + 16 + 4 * g) ^ sw)];
      }
#pragma unroll
      for (int ni = 0; ni < NI; ++ni) {
        const int row = wc * (TN / 2) + ni * 16 + lr;
        const int sw = (row & 7) << 3;
        bf[ni].q.lo = *(const unsigned long long*)&Bs[row * 64 + ((kk * 32 + 4 * g) ^ sw)];
        bf[ni].q.hi = *(const unsigned long long*)&Bs[row * 64 + ((kk * 32 + 16 + 4 * g) ^ sw)];
      }
#pragma unroll
      for (int mi = 0; mi < MI; ++mi)
#pragma unroll
        for (int ni = 0; ni < NI; ++ni)
          acc[mi][ni] = __builtin_amdgcn_mfma_f32_16x16x32_bf16(af[mi].v, bf[ni].v, acc[mi][ni], 0, 0, 0);
    }
    __syncthreads();
  }

#pragma unroll
  for (int mi = 0; mi < MI; ++mi) {
#pragma unroll
    for (int ni = 0; ni < NI; ++ni) {
      const int n = n0 + wc * (TN / 2) + ni * 16 + lr;
      const float bv = bias[n];
#pragma unroll
      for (int r = 0; r < 4; ++r) {
        const int m = m0 + wr * (TM / 2) + mi * 16 + 4 * g + r;
        float val = acc[mi][ni][r] + bv;
        if constexpr (MODE == 0) {
          const int s = n >> 8, hh = (n >> 5) & 7, dh = n & 31;
          const int bb = m >> 11, l = m & (L_ - 1);
          if (s == 0) {
            outb0[((size_t)(bb * H_ + hh) * L_ + l) * DH_ + dh] =
                f2bf(val * (0.17677669529663687f * LOG2E));
          } else if (s == 1) {
            outb1[((size_t)(bb * H_ + hh) * L_ + l) * DH_ + dh] = f2bf(val);
          } else {
            outb2[((size_t)(bb * H_ + hh) * DH_ + dh) * L_ + l] = f2bf(val);
          }
        } else if constexpr (MODE == 1) {
          const size_t o = (size_t)m * D_ + n;
          outf[o] = val + resid[o];
        } else if constexpr (MODE == 2) {
          outb0[(size_t)m * MLP_ + n] = f2bf(fmaxf(val, 0.f));
        } else {
          const size_t o = (size_t)m * D_ + n;
          outf[o] = val + resid[o];
        }
      }
    }
  }
}

// ---------------- flash attention ----------------
// 4 waves * 16 q = 64 q / block; KV chunk 64. log2-domain softmax.
__launch_bounds__(256)
__global__ void attn_k(const unsigned short* __restrict__ qb,
                       const unsigned short* __restrict__ kb,
                       const unsigned short* __restrict__ vT,
                       const int* __restrict__ mask,
                       const float* __restrict__ relb,
                       unsigned short* __restrict__ aout)
{
  __shared__ alignas(16) unsigned short Ks[64 * 40];   // padded rows (80B): conflict-free frag reads
  __shared__ alignas(16) unsigned short Vs[32 * 64];   // XOR-swizzled rows (gll16-staged)
  __shared__ alignas(16) float biasv[36];
  __shared__ alignas(16) float maskadd[64];
  const int tid = threadIdx.x;
  const int lane = tid & 63, wv = tid >> 6;
  const int lr = lane & 15, g = lane >> 4;
  const int bh = blockIdx.y, b = bh >> 3, h = bh & 7;
  const size_t bhoff = (size_t)bh * (L_ * DH_);
  if (tid < 33) biasv[tid] = relb[tid * H_ + h] * LOG2E;
  const float bias_lo = relb[h] * LOG2E;
  const float bias_hi = relb[32 * H_ + h] * LOG2E;
  const int qw0 = blockIdx.x * 64 + wv * 16;

  FragU qf;
  {
    const unsigned short* qr = qb + bhoff + (size_t)(qw0 + lr) * DH_;
    qf.q.lo = *(const unsigned long long*)(qr + 4 * g);
    qf.q.hi = *(const unsigned long long*)(qr + 16 + 4 * g);
  }
  f32x4 O0 = (f32x4)(0.f), O1 = (f32x4)(0.f);
  float m_run = -1e30f, ssum = 0.f;
  const f32x4 z4 = (f32x4)(0.f);
  const int krow = tid >> 2, kc8 = tid & 3;
  const int vrow = wv * 8 + (lane >> 3), vjj = lane & 7;

  for (int ch = 0; ch < L_ / 64; ++ch) {
    const int kvbase = ch * 64;
    *(int4*)&Ks[krow * 40 + kc8 * 8] =
        *(const int4*)(kb + bhoff + (size_t)(kvbase + krow) * DH_ + kc8 * 8);
    GLL16(vT + ((size_t)bh * DH_ + vrow) * L_ + kvbase + ((vjj ^ (vrow & 7)) * 8),
          &Vs[wv * 512]);
    if (tid < 64) maskadd[tid] = mask[b * L_ + kvbase + tid] ? -1e9f : 0.f;
    __syncthreads();

    FragU kf[4];
#pragma unroll
    for (int jt = 0; jt < 4; ++jt) {
      const int base = (jt * 16 + lr) * 40;
      kf[jt].q.lo = *(const unsigned long long*)&Ks[base + 4 * g];
      kf[jt].q.hi = *(const unsigned long long*)&Ks[base + 16 + 4 * g];
    }
    FragU vf[2][2];
#pragma unroll
    for (int dt = 0; dt < 2; ++dt)
#pragma unroll
      for (int jh = 0; jh < 2; ++jh) {
        const int row = dt * 16 + lr;
        const int sw = (row & 7) << 3;
        vf[dt][jh].q.lo = *(const unsigned long long*)&Vs[row * 64 + ((jh * 32 + 4 * g) ^ sw)];
        vf[dt][jh].q.hi = *(const unsigned long long*)&Vs[row * 64 + ((jh * 32 + 16 + 4 * g) ^ sw)];
      }
    f32x4 mf[4];
#pragma unroll
    for (int jt = 0; jt < 4; ++jt) mf[jt] = *(const f32x4*)(maskadd + jt * 16 + 4 * g);

    f32x4 sT[4];
#pragma unroll
    for (int jt = 0; jt < 4; ++jt)
      sT[jt] = __builtin_amdgcn_mfma_f32_16x16x32_bf16(kf[jt].v, qf.v, z4, 0, 0, 0);

    float p[4][4];
    const int dlt = kvbase - qw0;
    if (dlt >= 32 || dlt <= -80) {            // whole tile beyond the +-16 ramp
      const float badd = (dlt > 0) ? bias_hi : bias_lo;
#pragma unroll
      for (int jt = 0; jt < 4; ++jt)
#pragma unroll
        for (int r = 0; r < 4; ++r) p[jt][r] = sT[jt][r] + badd + mf[jt][r];
    } else {
#pragma unroll
      for (int jt = 0; jt < 4; ++jt)
#pragma unroll
        for (int r = 0; r < 4; ++r) {
          int rel = kvbase + jt * 16 + 4 * g + r - (qw0 + lr);
          rel = rel < -16 ? -16 : (rel > 16 ? 16 : rel);
          p[jt][r] = sT[jt][r] + biasv[rel + 16] + mf[jt][r];
        }
    }
    float mloc = -3e38f;
#pragma unroll
    for (int jt = 0; jt < 4; ++jt)
#pragma unroll
      for (int r = 0; r < 4; ++r) mloc = fmaxf(mloc, p[jt][r]);
    mloc = fmaxf(mloc, __shfl_xor(mloc, 16));
    mloc = fmaxf(mloc, __shfl_xor(mloc, 32));
    float m_new = m_run;
    if (!__all(mloc <= m_run + 8.f)) {        // defer-max (T13): skip rescale on small growth
      m_new = fmaxf(m_run, mloc);
      const float corr = fexp2(m_run - m_new);
#pragma unroll
      for (int r = 0; r < 4; ++r) {
        const float c = __shfl(corr, 4 * g + r);
        O0[r] *= c; O1[r] *= c;
      }
      ssum *= corr;
      m_run = m_new;
    }
    float psum = 0.f;
#pragma unroll
    for (int jt = 0; jt < 4; ++jt)
#pragma unroll
      for (int r = 0; r < 4; ++r) {
        const float e = fexp2(p[jt][r] - m_new);
        p[jt][r] = e; psum += e;
      }
    psum += __shfl_xor(psum, 16);
    psum += __shfl_xor(psum, 32);
    ssum += psum;

    FragU a0, a1;                              // T12: packed bf16 convert
    a0.u[0] = cvt_pk_bf16(p[0][0], p[0][1]);
    a0.u[1] = cvt_pk_bf16(p[0][2], p[0][3]);
    a0.u[2] = cvt_pk_bf16(p[1][0], p[1][1]);
    a0.u[3] = cvt_pk_bf16(p[1][2], p[1][3]);
    a1.u[0] = cvt_pk_bf16(p[2][0], p[2][1]);
    a1.u[1] = cvt_pk_bf16(p[2][2], p[2][3]);
    a1.u[2] = cvt_pk_bf16(p[3][0], p[3][1]);
    a1.u[3] = cvt_pk_bf16(p[3][2], p[3][3]);

    O0 = __builtin_amdgcn_mfma_f32_16x16x32_bf16(a0.v, vf[0][0].v, O0, 0, 0, 0);
    O0 = __builtin_amdgcn_mfma_f32_16x16x32_bf16(a1.v, vf[0][1].v, O0, 0, 0, 0);
    O1 = __builtin_amdgcn_mfma_f32_16x16x32_bf16(a0.v, vf[1][0].v, O1, 0, 0, 0);
    O1 = __builtin_amdgcn_mfma_f32_16x16x32_bf16(a1.v, vf[1][1].v, O1, 0, 0, 0);
    __syncthreads();
  }

#pragma unroll
  for (int r = 0; r < 4; ++r) {
    const float sden = __shfl(ssum, 4 * g + r);
    const float inv = 1.f / sden;
    const int qo = qw0 + 4 * g + r;
    unsigned short* orow = aout + ((size_t)(b * L_ + qo)) * D_ + h * DH_;
    orow[lr]      = f2bf(O0[r] * inv);
    orow[16 + lr] = f2bf(O1[r] * inv);
  }
}

// ---------------- LayerNorm (one wave per row) ----------------
__launch_bounds__(256)
__global__ void ln_k(const float* __restrict__ y, const float* __restrict__ gg,
                     const float* __restrict__ bb, float* __restrict__ outf,
                     unsigned short* __restrict__ outb)
{
  const int tid = threadIdx.x, lane = tid & 63, wv = tid >> 6;
  const int row = blockIdx.x * 4 + wv;
  const size_t base = (size_t)row * D_ + lane * 4;
  const float4 v = *(const float4*)(y + base);
  float s = v.x + v.y + v.z + v.w;
#pragma unroll
  for (int m = 1; m < 64; m <<= 1) s += __shfl_xor(s, m);
  const float mu = s * (1.f / D_);
  const float dx = v.x - mu, dy = v.y - mu, dz = v.z - mu, dw = v.w - mu;
  float q = dx * dx + dy * dy + dz * dz + dw * dw;
#pragma unroll
  for (int m = 1; m < 64; m <<= 1) q += __shfl_xor(q, m);
  const float rstd = rsqrtf(q * (1.f / D_) + 1e-5f);
  const float4 g4 = *(const float4*)(gg + lane * 4);
  const float4 b4 = *(const float4*)(bb + lane * 4);
  float4 o;
  o.x = dx * rstd * g4.x + b4.x;
  o.y = dy * rstd * g4.y + b4.y;
  o.z = dz * rstd * g4.z + b4.z;
  o.w = dw * rstd * g4.w + b4.w;
  *(float4*)(outf + base) = o;
  if (outb) *(unsigned long long*)(outb + base) = pack4(o.x, o.y, o.z, o.w);
}

// ---------------- launch ----------------
extern "C" void kernel_launch(void* const* d_in, const int* in_sizes, int n_in,
                              void* d_out, int out_size, void* d_ws, size_t ws_size,
                              hipStream_t stream) {
  (void)in_sizes; (void)n_in; (void)out_size; (void)ws_size;
  const float* x    = (const float*)d_in[0];
  const int*   mask = (const int*)d_in[1];
  const float* Wqkv = (const float*)d_in[2];
  const float* bqkv = (const float*)d_in[3];
  const float* Wo   = (const float*)d_in[4];
  const float* bo   = (const float*)d_in[5];
  const float* ln1g = (const float*)d_in[6];
  const float* ln1b = (const float*)d_in[7];
  const float* W1   = (const float*)d_in[8];
  const float* b1   = (const float*)d_in[9];
  const float* W2   = (const float*)d_in[10];
  const float* b2   = (const float*)d_in[11];
  const float* ln2g = (const float*)d_in[12];
  const float* ln2b = (const float*)d_in[13];
  const float* relb = (const float*)d_in[14];

  size_t off = 0;
  char* wsb = (char*)d_ws;
  auto carve = [&](size_t bytes) -> void* {
    void* p = wsb + off;
    off += (bytes + 255) & ~(size_t)255;
    return p;
  };
  const size_t tokb = (size_t)B_ * L_;
  unsigned short* xb    = (unsigned short*)carve(tokb * D_ * 2);
  unsigned short* qb    = (unsigned short*)carve(tokb * D_ * 2);
  unsigned short* kbuf  = (unsigned short*)carve(tokb * D_ * 2);
  unsigned short* vTb   = (unsigned short*)carve(tokb * D_ * 2);
  unsigned short* attnb = (unsigned short*)carve(tokb * D_ * 2);
  unsigned short* wqkvt = (unsigned short*)carve((size_t)3 * D_ * D_ * 2);
  unsigned short* wot   = (unsigned short*)carve((size_t)D_ * D_ * 2);
  unsigned short* w1t   = (unsigned short*)carve((size_t)D_ * MLP_ * 2);
  unsigned short* w2t   = (unsigned short*)carve((size_t)D_ * MLP_ * 2);
  float*          ybuf  = (float*)carve(tokb * D_ * 4);
  float*          x1    = (float*)carve(tokb * D_ * 4);
  unsigned short* x1b   = (unsigned short*)carve(tokb * D_ * 2);
  unsigned short* hbuf  = (unsigned short*)carve(tokb * MLP_ * 2);

  cvt_k<<<(tokb * D_ / 4 + 255) / 256, 256, 0, stream>>>(x, xb, (int)(tokb * D_ / 4));
  prep_w<<<3072, 256, 0, stream>>>(Wqkv, Wo, W1, W2, wqkvt, wot, w1t, w2t);

  gemm_k<0, 64, 128><<<dim3(3 * D_ / 128, tokb / 64), 256, 0, stream>>>(
      xb, wqkvt, bqkv, nullptr, nullptr, qb, kbuf, vTb, D_);
  attn_k<<<dim3(L_ / 64, B_ * H_), 256, 0, stream>>>(qb, kbuf, vTb, mask, relb, attnb);
  gemm_k<1, 64, 64><<<dim3(D_ / 64, tokb / 64), 256, 0, stream>>>(
      attnb, wot, bo, x, ybuf, nullptr, nullptr, nullptr, D_);
  ln_k<<<tokb / 4, 256, 0, stream>>>(ybuf, ln1g, ln1b, x1, x1b);
  gemm_k<2, 64, 128><<<dim3(MLP_ / 128, tokb / 64), 256, 0, stream>>>(
      x1b, w1t, b1, nullptr, nullptr, hbuf, nullptr, nullptr, D_);
  gemm_k<3, 64, 64><<<dim3(D_ / 64, tokb / 64), 256, 0, stream>>>(
      hbuf, w2t, b2, x1, ybuf, nullptr, nullptr, nullptr, MLP_);
  ln_k<<<tokb / 4, 256, 0, stream>>>(ybuf, ln2g, ln2b, (float*)d_out, nullptr);
}